// Round 16
// baseline (120.390 us; speedup 1.0000x reference)
//
#include <hip/hip_runtime.h>
#include <hip/hip_bf16.h>
#include <math.h>

#define T_DIM 2048
#define B_DIM 16
#define M_DIM 512
#define H_DIM 256
#define KC 512
#define K_DIM 512
#define CHUNK 64
#define NCHUNK 32
#define NTILE 16            // K / 32 (pre-tiled granule count per 128-panel)

typedef unsigned short ushort_t;
typedef __attribute__((ext_vector_type(8))) short short8;
typedef __attribute__((ext_vector_type(8))) unsigned short ushort8;
typedef __attribute__((ext_vector_type(4))) float f32x4;

// ---- workspace layout (float offsets); total 17301504 floats = 69.2 MB ----
#define WS_CARRY 0            // 262144 floats (32*16*512)
#define WS_WB_BF 262144       // 262144 ushorts tiled
#define WS_WC_BF 393216       // 262144 ushorts tiled
#define WS_XB    524288       // 16777216 ushorts: X bf16 TILED
#define WS_BU    8912896      // 16777216 ushorts: Bu TILED, then H in place

// tiled index (ushorts): element (n,k) -> ((n/128)*16 + k/32)*4096 +
//   ((k/8)%4)*1024 + (n%128)*8 + k%8   — linear LDS staging order.
__device__ inline int tidx(int n, int k) {
    return (((n >> 7) * 16 + (k >> 5)) << 12) + (((k >> 3) & 3) << 10)
         + ((n & 127) << 3) + (k & 7);
}

__device__ inline ushort_t f2bf(float f) {
    __hip_bfloat16 h = __float2bfloat16(f);
    return *reinterpret_cast<ushort_t*>(&h);
}
__device__ inline float bf2f(ushort_t u) {
    union { unsigned int i; float f; } v;
    v.i = ((unsigned int)u) << 16;
    return v.f;
}

// Merged prep: blocks [0,8192) convert X fp32 -> bf16 TILED; blocks
// [8192,9216) build the bf16 pre-tiled weights.
__global__ __launch_bounds__(256) void prep_all(
        const float* __restrict__ X, ushort_t* __restrict__ Xb,
        const float* __restrict__ B_re, const float* __restrict__ B_im,
        const float* __restrict__ gamma_log,
        const float* __restrict__ C_re, const float* __restrict__ C_im,
        ushort_t* __restrict__ wb, ushort_t* __restrict__ wc) {
    int bid = blockIdx.x;
    if (bid < 8192) {
        int f = bid * 256 + threadIdx.x;          // 0..2097151
        int n = f >> 6, ko = f & 63;
        const float* p = X + (size_t)n * 512 + ko * 8;
        float4 a = *(const float4*)p;
        float4 b = *(const float4*)(p + 4);
        ushort8 u;
        u[0] = f2bf(a.x); u[1] = f2bf(a.y); u[2] = f2bf(a.z); u[3] = f2bf(a.w);
        u[4] = f2bf(b.x); u[5] = f2bf(b.y); u[6] = f2bf(b.z); u[7] = f2bf(b.w);
        *(ushort8*)(&Xb[(((n >> 7) * 16 + (ko >> 2)) << 12) + ((ko & 3) << 10)
                        + ((n & 127) << 3)]) = u;
    } else {
        int idx = (bid - 8192) * 256 + threadIdx.x;  // 0..262143
        int e    = idx & 7;
        int slot = (idx >> 3) & 511;
        int row  = slot & 127;
        int ks   = slot >> 7;
        int t    = (idx >> 12) & 15;
        int blk  = idx >> 16;
        int j = blk * 128 + row;
        int k = t * 32 + ks * 8 + e;
        float v;
        if (j < 256) v = expf(gamma_log[j])       * B_re[j * 512 + k];
        else         v = expf(gamma_log[j - 256]) * B_im[(j - 256) * 512 + k];
        wb[idx] = f2bf(v);
        float w;
        if (k < 256) w =  C_re[j * 256 + k];
        else         w = -C_im[j * 256 + (k - 256)];
        wc[idx] = f2bf(w);
    }
}

// NT GEMM via MFMA bf16, 256x128 tile, BK=64, 4 waves (256 thr), 2 blocks/CU.
// R12/R14-proven 2-phase loop (2 LDS dbufs for A, unroll-2 static indices,
// plain __syncthreads). B operand (weights, L2-resident) read direct
// global->register, issued FIRST each step so its compiler vmcnt wait leaves
// the A staging loads in flight (R14). Grid 512 = 2 blocks/CU: co-resident
// block's waves cover the per-step barrier drain (m114 overlap mechanism).
// STAGING FIX vs R15: global_load_lds LDS dest is wave-uniform base +
// lane*16B (m104/m108) — each instruction must have per-lane dest stride
// exactly 16B. Chunk-contiguous map: thread stages chunks c=tid and
// c=tid+256 of each 4096-ushort granule (dest c*8 ushorts), NOT a 32B/lane
// interleave (R15's bug: HW wrote base+lane*16 while code assumed lane*32).
// MODE 0 (GEMM1): swapped operands mfma(W,X) -> packed uint2 tiled Bu out.
// MODE 1 (GEMM2): normal order, fp32 natural out + D[col]*Xb epilogue.
template <int MODE>
__global__ __launch_bounds__(256) void gemm_mfma(
    const ushort_t* __restrict__ A, const ushort_t* __restrict__ W,
    void* __restrict__ Cv, const float* __restrict__ Dv,
    const ushort_t* __restrict__ Xb) {
    __shared__ ushort_t Asl[2][4][4096];   // [buf][q*2+kk][slot] : 64KB
    const int tid = threadIdx.x;           // 0..255
    const int id = blockIdx.x;
    const int rb = ((id >> 5) << 3) + (id & 7);   // row-panel-pair 0..127
    const int nb = (id >> 3) & 3;                 // col-panel 0..3 (128 wide)
    const int bm = rb << 8, bn = nb << 7;
    const int lane = tid & 63, wid = tid >> 6;    // 4 waves
    const int wr  = (wid >> 1) << 7;       // 0 / 128
    const int wcc = (wid & 1) << 6;        // 0 / 64
    const int l16 = lane & 15, ksl = lane >> 4;
    const int c0 = tid, c1 = tid + 256;    // staging chunks (16B each)

    f32x4 acc[MODE == 0 ? 4 : 8][MODE == 0 ? 8 : 4] = {};

    // Direct-global W frag bases: col j = bn + wcc + n*16 + l16; granule
    // (t*2+kk) advances by 4096 ushorts.
    size_t wbase[4];
#pragma unroll
    for (int n = 0; n < 4; ++n) {
        int j = bn + wcc + n * 16 + l16;
        wbase[n] = (size_t)((j >> 7) * 16) * 4096 + (size_t)ksl * 1024
                 + (size_t)(j & 127) * 8;
    }

    auto stage = [&](int t, int buf) {     // A only: 8 gload_lds / thread
#pragma unroll
        for (int q = 0; q < 2; ++q)
#pragma unroll
            for (int kk = 0; kk < 2; ++kk) {
                size_t ab = ((size_t)((2 * rb + q) * NTILE + (2 * t + kk))) * 4096;
                __builtin_amdgcn_global_load_lds(
                    (const __attribute__((address_space(1))) void*)(A + ab + c0 * 8),
                    (__attribute__((address_space(3))) void*)(&Asl[buf][q * 2 + kk][c0 * 8]),
                    16, 0, 0);
                __builtin_amdgcn_global_load_lds(
                    (const __attribute__((address_space(1))) void*)(A + ab + c1 * 8),
                    (__attribute__((address_space(3))) void*)(&Asl[buf][q * 2 + kk][c1 * 8]),
                    16, 0, 0);
            }
    };

    stage(0, 0);
    __syncthreads();

    int cur = 0;
#pragma unroll 2
    for (int t = 0; t < 8; ++t) {
        const int nxt = cur ^ 1;
        // B frags for this step FIRST (their vmcnt wait excludes staging)
        short8 bfr2[2][4];
#pragma unroll
        for (int kk = 0; kk < 2; ++kk)
#pragma unroll
            for (int n = 0; n < 4; ++n)
                bfr2[kk][n] = *(const short8*)(&W[wbase[n] + (size_t)(t * 2 + kk) * 4096]);
        if (t + 1 < 8) stage(t + 1, nxt);
#pragma unroll
        for (int kk = 0; kk < 2; ++kk) {
            short8 afr[8];
#pragma unroll
            for (int m = 0; m < 8; ++m) {
                int row = wr + m * 16 + l16;       // 0..255
                afr[m] = *(const short8*)(&Asl[cur][(row >> 7) * 2 + kk]
                                              [ksl * 1024 + (row & 127) * 8]);
            }
            if constexpr (MODE == 0) {
#pragma unroll
                for (int i = 0; i < 4; ++i)       // i: W-frag (k axis)
#pragma unroll
                    for (int j = 0; j < 8; ++j)   // j: X-frag (n axis)
                        acc[i][j] = __builtin_amdgcn_mfma_f32_16x16x32_bf16(
                            bfr2[kk][i], afr[j], acc[i][j], 0, 0, 0);
            } else {
#pragma unroll
                for (int i = 0; i < 8; ++i)       // i: A-frag (H rows)
#pragma unroll
                    for (int j = 0; j < 4; ++j)   // j: W-frag (out cols)
                        acc[i][j] = __builtin_amdgcn_mfma_f32_16x16x32_bf16(
                            afr[i], bfr2[kk][j], acc[i][j], 0, 0, 0);
            }
        }
        __syncthreads();
        cur = nxt;
    }

    const int fr = (lane >> 4) << 2;
    if constexpr (MODE == 0) {
        // D row axis = W-col k (4 consecutive), D col axis (l16) = X-row n.
        ushort_t* Bu = (ushort_t*)Cv;
#pragma unroll
        for (int i = 0; i < 4; ++i) {
            int k0 = bn + wcc + i * 16 + fr;      // 4-aligned k quad
#pragma unroll
            for (int j = 0; j < 8; ++j) {
                int n = bm + wr + j * 16 + l16;
                uint2 p;
                p.x = (unsigned int)f2bf(acc[i][j][0])
                    | ((unsigned int)f2bf(acc[i][j][1]) << 16);
                p.y = (unsigned int)f2bf(acc[i][j][2])
                    | ((unsigned int)f2bf(acc[i][j][3]) << 16);
                size_t off = ((size_t)((n >> 7) * 16 + (k0 >> 5)) << 12)
                           + (((k0 >> 3) & 3) << 10) + ((n & 127) << 3) + (k0 & 7);
                *(uint2*)(&Bu[off]) = p;
            }
        }
    } else {
        // natural fp32 out: row = H-row, col via l16 (64B coalesced)
#pragma unroll
        for (int i = 0; i < 8; ++i) {
#pragma unroll
            for (int j = 0; j < 4; ++j) {
#pragma unroll
                for (int r = 0; r < 4; ++r) {
                    int row = bm + wr + i * 16 + fr + r;
                    int col = bn + wcc + j * 16 + l16;
                    size_t o = (size_t)row * 512 + col;
                    ((float*)Cv)[o] = acc[i][j][r] + Dv[col] * bf2f(Xb[tidx(row, col)]);
                }
            }
        }
    }
}

// Scan pass A: block = (chunk c, h-slab s); threads = 16 b x 16 h-pairs.
// Batch-8 loads (addresses independent of recurrence) to hide HBM latency.
__global__ __launch_bounds__(256) void scan_local(const float* __restrict__ nu_log,
        const float* __restrict__ theta_log, float* __restrict__ ws) {
    const int c = blockIdx.x;
    const int s = blockIdx.y;
    const int b = threadIdx.x >> 4;
    const int h0 = s * 32 + (threadIdx.x & 15) * 2;
    float lr[2], li[2];
#pragma unroll
    for (int q = 0; q < 2; ++q) {
        float nu = expf(nu_log[h0 + q]);
        float th = expf(theta_log[h0 + q]);
        float r  = expf(-nu);
        lr[q] = r * cosf(th); li[q] = r * sinf(th);
    }
    const ushort_t* Bu = (const ushort_t*)(ws + WS_BU);
    float hr[2] = {0.f, 0.f}, hi[2] = {0.f, 0.f};
    for (int l0 = 0; l0 < CHUNK; l0 += 8) {
        unsigned int vre[8], vim[8];
#pragma unroll
        for (int u = 0; u < 8; ++u) {
            int n = (c * CHUNK + l0 + u) * B_DIM + b;
            vre[u] = *(const unsigned int*)(&Bu[tidx(n, h0)]);
            vim[u] = *(const unsigned int*)(&Bu[tidx(n, h0 + 256)]);
        }
#pragma unroll
        for (int u = 0; u < 8; ++u) {
#pragma unroll
            for (int q = 0; q < 2; ++q) {
                float br = bf2f((ushort_t)(q ? (vre[u] >> 16) : (vre[u] & 0xffff)));
                float bi = bf2f((ushort_t)(q ? (vim[u] >> 16) : (vim[u] & 0xffff)));
                float nr = fmaf(lr[q], hr[q], fmaf(-li[q], hi[q], br));
                float ni = fmaf(lr[q], hi[q], fmaf(li[q], hr[q], bi));
                hr[q] = nr; hi[q] = ni;
            }
        }
    }
    size_t cb = (size_t)(c * B_DIM + b) * KC;
    *(float2*)(&ws[WS_CARRY + cb + h0])       = make_float2(hr[0], hr[1]);
    *(float2*)(&ws[WS_CARRY + cb + 256 + h0]) = make_float2(hi[0], hi[1]);
}

// Pass B: sequential over 32 chunk aggregates; h_final planar re/im to out tail.
__global__ __launch_bounds__(256) void scan_carry(const float* __restrict__ nu_log,
        const float* __restrict__ theta_log, float* __restrict__ ws,
        const float* __restrict__ h_re, const float* __restrict__ h_im,
        float* __restrict__ out, int out_size) {
    const int b = blockIdx.x;
    const int h = threadIdx.x;
    const float nu = expf(nu_log[h]);
    const float th = expf(theta_log[h]);
    const float rL  = expf(-64.f * nu);
    const float thL = 64.f * th;
    const float Lr = rL * cosf(thL), Li = rL * sinf(thL);
    float cr = h_re[b * H_DIM + h], ci = h_im[b * H_DIM + h];
    for (int c = 0; c < NCHUNK; ++c) {
        size_t cidx = ((size_t)(c * B_DIM + b)) * KC + h;
        float sr = ws[WS_CARRY + cidx], si = ws[WS_CARRY + cidx + 256];
        ws[WS_CARRY + cidx]       = cr;
        ws[WS_CARRY + cidx + 256] = ci;
        float nr = fmaf(Lr, cr, fmaf(-Li, ci, sr));
        float ni = fmaf(Lr, ci, fmaf(Li, cr, si));
        cr = nr; ci = ni;
    }
    const size_t base = (size_t)T_DIM * B_DIM * M_DIM;
    const size_t idx  = (size_t)b * H_DIM + h;
    size_t ore = base + idx;
    size_t oim = base + (size_t)B_DIM * H_DIM + idx;
    if (ore < (size_t)out_size) out[ore] = cr;
    if (oim < (size_t)out_size) out[oim] = ci;
}

// Pass C: replay chunk from carry-in; overwrite Bu IN PLACE (tiled) with h_t.
__global__ __launch_bounds__(256) void scan_apply(const float* __restrict__ nu_log,
        const float* __restrict__ theta_log, float* __restrict__ ws) {
    const int c = blockIdx.x;
    const int s = blockIdx.y;
    const int b = threadIdx.x >> 4;
    const int h0 = s * 32 + (threadIdx.x & 15) * 2;
    float lr[2], li[2];
#pragma unroll
    for (int q = 0; q < 2; ++q) {
        float nu = expf(nu_log[h0 + q]);
        float th = expf(theta_log[h0 + q]);
        float r  = expf(-nu);
        lr[q] = r * cosf(th); li[q] = r * sinf(th);
    }
    ushort_t* Bu = (ushort_t*)(ws + WS_BU);
    size_t cb = (size_t)(c * B_DIM + b) * KC;
    float2 f2r = *(const float2*)(&ws[WS_CARRY + cb + h0]);
    float2 f2i = *(const float2*)(&ws[WS_CARRY + cb + 256 + h0]);
    float hr[2] = {f2r.x, f2r.y}, hi[2] = {f2i.x, f2i.y};
    for (int l0 = 0; l0 < CHUNK; l0 += 8) {
        unsigned int vre[8], vim[8];
        int ire[8], iim[8];
#pragma unroll
        for (int u = 0; u < 8; ++u) {
            int n = (c * CHUNK + l0 + u) * B_DIM + b;
            ire[u] = tidx(n, h0);
            iim[u] = tidx(n, h0 + 256);
            vre[u] = *(const unsigned int*)(&Bu[ire[u]]);
            vim[u] = *(const unsigned int*)(&Bu[iim[u]]);
        }
#pragma unroll
        for (int u = 0; u < 8; ++u) {
#pragma unroll
            for (int q = 0; q < 2; ++q) {
                float br = bf2f((ushort_t)(q ? (vre[u] >> 16) : (vre[u] & 0xffff)));
                float bi = bf2f((ushort_t)(q ? (vim[u] >> 16) : (vim[u] & 0xffff)));
                float nr = fmaf(lr[q], hr[q], fmaf(-li[q], hi[q], br));
                float ni = fmaf(lr[q], hi[q], fmaf(li[q], hr[q], bi));
                hr[q] = nr; hi[q] = ni;
            }
            *(unsigned int*)(&Bu[ire[u]]) =
                (unsigned int)f2bf(hr[0]) | ((unsigned int)f2bf(hr[1]) << 16);
            *(unsigned int*)(&Bu[iim[u]]) =
                (unsigned int)f2bf(hi[0]) | ((unsigned int)f2bf(hi[1]) << 16);
        }
    }
}

extern "C" void kernel_launch(void* const* d_in, const int* in_sizes, int n_in,
                              void* d_out, int out_size, void* d_ws, size_t ws_size,
                              hipStream_t stream) {
    const float* inputs    = (const float*)d_in[0];
    const float* h_re      = (const float*)d_in[1];
    const float* h_im      = (const float*)d_in[2];
    const float* nu_log    = (const float*)d_in[3];
    const float* theta_log = (const float*)d_in[4];
    const float* gamma_log = (const float*)d_in[5];
    const float* B_re      = (const float*)d_in[6];
    const float* B_im      = (const float*)d_in[7];
    const float* C_re      = (const float*)d_in[8];
    const float* C_im      = (const float*)d_in[9];
    const float* Dv        = (const float*)d_in[10];
    float* out = (float*)d_out;
    float* ws  = (float*)d_ws;
    ushort_t* wb = (ushort_t*)(ws + WS_WB_BF);
    ushort_t* wc = (ushort_t*)(ws + WS_WC_BF);
    ushort_t* xb = (ushort_t*)(ws + WS_XB);
    ushort_t* bu = (ushort_t*)(ws + WS_BU);

    prep_all<<<9216, 256, 0, stream>>>(inputs, xb, B_re, B_im, gamma_log,
                                       C_re, C_im, wb, wc);

    // GEMM1: Bu = X . Wb^T (swapped MFMA; W direct-from-L2; tiled Bu out)
    gemm_mfma<0><<<512, 256, 0, stream>>>(xb, wb, (void*)bu, nullptr, nullptr);

    scan_local<<<dim3(NCHUNK, 8), 256, 0, stream>>>(nu_log, theta_log, ws);
    scan_carry<<<B_DIM, 256, 0, stream>>>(nu_log, theta_log, ws, h_re, h_im,
                                          out, out_size);
    scan_apply<<<dim3(NCHUNK, 8), 256, 0, stream>>>(nu_log, theta_log, ws);

    // GEMM2: Y = H . Wc^T + D*x  (W direct-from-L2; fp32 out + Xb epilogue)
    gemm_mfma<1><<<512, 256, 0, stream>>>(bu, wc, (void*)out, Dv, xb);
}

// Round 17
// 107.604 us; speedup vs baseline: 1.1188x; 1.1188x over previous
//
#include <hip/hip_runtime.h>
#include <hip/hip_bf16.h>
#include <math.h>

#define T_DIM 2048
#define B_DIM 16
#define M_DIM 512
#define H_DIM 256
#define KC 512
#define K_DIM 512
#define CHUNK 64
#define NCHUNK 32
#define NTILE 16            // K / 32 (pre-tiled granule count per 128-panel)

typedef unsigned short ushort_t;
typedef __attribute__((ext_vector_type(8))) short short8;
typedef __attribute__((ext_vector_type(8))) unsigned short ushort8;
typedef __attribute__((ext_vector_type(4))) float f32x4;

// ---- workspace layout (float offsets); total 17301504 floats = 69.2 MB ----
#define WS_CARRY 0            // 262144 floats (32*16*512) — raw chunk sums
#define WS_WB_BF 262144       // 262144 ushorts tiled
#define WS_WC_BF 393216       // 262144 ushorts tiled
#define WS_XB    524288       // 16777216 ushorts: X bf16 TILED
#define WS_BU    8912896      // 16777216 ushorts: Bu TILED, then H in place

// tiled index (ushorts): element (n,k) -> ((n/128)*16 + k/32)*4096 +
//   ((k/8)%4)*1024 + (n%128)*8 + k%8   — linear LDS staging order.
__device__ inline int tidx(int n, int k) {
    return (((n >> 7) * 16 + (k >> 5)) << 12) + (((k >> 3) & 3) << 10)
         + ((n & 127) << 3) + (k & 7);
}

__device__ inline ushort_t f2bf(float f) {
    __hip_bfloat16 h = __float2bfloat16(f);
    return *reinterpret_cast<ushort_t*>(&h);
}
__device__ inline float bf2f(ushort_t u) {
    union { unsigned int i; float f; } v;
    v.i = ((unsigned int)u) << 16;
    return v.f;
}

// Merged prep: blocks [0,8192) convert X fp32 -> bf16 TILED; blocks
// [8192,9216) build the bf16 pre-tiled weights.
__global__ __launch_bounds__(256) void prep_all(
        const float* __restrict__ X, ushort_t* __restrict__ Xb,
        const float* __restrict__ B_re, const float* __restrict__ B_im,
        const float* __restrict__ gamma_log,
        const float* __restrict__ C_re, const float* __restrict__ C_im,
        ushort_t* __restrict__ wb, ushort_t* __restrict__ wc) {
    int bid = blockIdx.x;
    if (bid < 8192) {
        int f = bid * 256 + threadIdx.x;          // 0..2097151
        int n = f >> 6, ko = f & 63;
        const float* p = X + (size_t)n * 512 + ko * 8;
        float4 a = *(const float4*)p;
        float4 b = *(const float4*)(p + 4);
        ushort8 u;
        u[0] = f2bf(a.x); u[1] = f2bf(a.y); u[2] = f2bf(a.z); u[3] = f2bf(a.w);
        u[4] = f2bf(b.x); u[5] = f2bf(b.y); u[6] = f2bf(b.z); u[7] = f2bf(b.w);
        *(ushort8*)(&Xb[(((n >> 7) * 16 + (ko >> 2)) << 12) + ((ko & 3) << 10)
                        + ((n & 127) << 3)]) = u;
    } else {
        int idx = (bid - 8192) * 256 + threadIdx.x;  // 0..262143
        int e    = idx & 7;
        int slot = (idx >> 3) & 511;
        int row  = slot & 127;
        int ks   = slot >> 7;
        int t    = (idx >> 12) & 15;
        int blk  = idx >> 16;
        int j = blk * 128 + row;
        int k = t * 32 + ks * 8 + e;
        float v;
        if (j < 256) v = expf(gamma_log[j])       * B_re[j * 512 + k];
        else         v = expf(gamma_log[j - 256]) * B_im[(j - 256) * 512 + k];
        wb[idx] = f2bf(v);
        float w;
        if (k < 256) w =  C_re[j * 256 + k];
        else         w = -C_im[j * 256 + (k - 256)];
        wc[idx] = f2bf(w);
    }
}

// NT GEMM via MFMA bf16, 256x256 tile, BK=64, 8 waves (512 thr) — R12
// verbatim (the empirical optimum: R13-R16 variations all regressed or
// were neutral). 2-phase loop: 2 LDS dbufs, unroll-2 static indices,
// plain __syncthreads. Both operands staged via global_load_lds with the
// chunk-contiguous map (per-instruction lane-stride exactly 16B, m104).
// Grid 1-D 256: id = g*16 + j*8 + x -> rb = g*8+x (0..127), nb = j (0..1);
// 2 col-panels of a row-panel land on one XCD (L2 A-panel sharing).
// MODE 0 (GEMM1): swapped operands mfma(W,X) -> packed uint2 tiled Bu out.
// MODE 1 (GEMM2): normal order, fp32 natural out + D[col]*Xb epilogue.
template <int MODE>
__global__ __launch_bounds__(512) void gemm_mfma(
    const ushort_t* __restrict__ A, const ushort_t* __restrict__ W,
    void* __restrict__ Cv, const float* __restrict__ Dv,
    const ushort_t* __restrict__ Xb) {
    __shared__ ushort_t Asl[2][4][4096];   // [buf][q*2+kk][slot] : 64KB
    __shared__ ushort_t Bsl[2][4][4096];   // 64KB
    const int tid = threadIdx.x;           // 0..511
    const int id = blockIdx.x;
    const int rb = ((id >> 4) << 3) + (id & 7);   // row-panel-pair 0..127
    const int nb = (id >> 3) & 1;                 // col-panel-pair 0..1
    const int bm = rb << 8, bn = nb << 8;
    const int lane = tid & 63, wid = tid >> 6;    // 8 waves
    const int wr  = (wid >> 2) << 7;       // 0 / 128
    const int wcc = (wid & 3) << 6;        // 0,64,128,192
    const int l16 = lane & 15, ksl = lane >> 4;

    f32x4 acc[MODE == 0 ? 4 : 8][MODE == 0 ? 8 : 4] = {};

    auto stage = [&](int t, int buf) {
#pragma unroll
        for (int q = 0; q < 2; ++q) {
#pragma unroll
            for (int kk = 0; kk < 2; ++kk) {
                size_t ab = ((size_t)((2 * rb + q) * NTILE + (2 * t + kk))) * 4096;
                __builtin_amdgcn_global_load_lds(
                    (const __attribute__((address_space(1))) void*)(A + ab + tid * 8),
                    (__attribute__((address_space(3))) void*)(&Asl[buf][q * 2 + kk][tid * 8]),
                    16, 0, 0);
                size_t bb = ((size_t)((2 * nb + q) * NTILE + (2 * t + kk))) * 4096;
                __builtin_amdgcn_global_load_lds(
                    (const __attribute__((address_space(1))) void*)(W + bb + tid * 8),
                    (__attribute__((address_space(3))) void*)(&Bsl[buf][q * 2 + kk][tid * 8]),
                    16, 0, 0);
            }
        }
    };

    stage(0, 0);
    __syncthreads();

    int cur = 0;
#pragma unroll 2
    for (int t = 0; t < 8; ++t) {
        const int nxt = cur ^ 1;
        if (t + 1 < 8) stage(t + 1, nxt);
#pragma unroll
        for (int kk = 0; kk < 2; ++kk) {
            short8 afr[8], bfr[4];
#pragma unroll
            for (int m = 0; m < 8; ++m) {
                int row = wr + m * 16 + l16;       // 0..255
                afr[m] = *(const short8*)(&Asl[cur][(row >> 7) * 2 + kk]
                                              [ksl * 1024 + (row & 127) * 8]);
            }
#pragma unroll
            for (int n = 0; n < 4; ++n) {
                int col = wcc + n * 16 + l16;      // 0..255
                bfr[n] = *(const short8*)(&Bsl[cur][(col >> 7) * 2 + kk]
                                              [ksl * 1024 + (col & 127) * 8]);
            }
            if constexpr (MODE == 0) {
#pragma unroll
                for (int i = 0; i < 4; ++i)       // i: W-frag (k axis)
#pragma unroll
                    for (int j = 0; j < 8; ++j)   // j: X-frag (n axis)
                        acc[i][j] = __builtin_amdgcn_mfma_f32_16x16x32_bf16(
                            bfr[i], afr[j], acc[i][j], 0, 0, 0);
            } else {
#pragma unroll
                for (int i = 0; i < 8; ++i)       // i: A-frag (H rows)
#pragma unroll
                    for (int j = 0; j < 4; ++j)   // j: W-frag (out cols)
                        acc[i][j] = __builtin_amdgcn_mfma_f32_16x16x32_bf16(
                            afr[i], bfr[j], acc[i][j], 0, 0, 0);
            }
        }
        __syncthreads();
        cur = nxt;
    }

    const int fr = (lane >> 4) << 2;
    if constexpr (MODE == 0) {
        // D row axis = W-col k (4 consecutive), D col axis (l16) = X-row n.
        ushort_t* Bu = (ushort_t*)Cv;
#pragma unroll
        for (int i = 0; i < 4; ++i) {
            int k0 = bn + wcc + i * 16 + fr;      // 4-aligned k quad
#pragma unroll
            for (int j = 0; j < 8; ++j) {
                int n = bm + wr + j * 16 + l16;
                uint2 p;
                p.x = (unsigned int)f2bf(acc[i][j][0])
                    | ((unsigned int)f2bf(acc[i][j][1]) << 16);
                p.y = (unsigned int)f2bf(acc[i][j][2])
                    | ((unsigned int)f2bf(acc[i][j][3]) << 16);
                size_t off = ((size_t)((n >> 7) * 16 + (k0 >> 5)) << 12)
                           + (((k0 >> 3) & 3) << 10) + ((n & 127) << 3) + (k0 & 7);
                *(uint2*)(&Bu[off]) = p;
            }
        }
    } else {
        // natural fp32 out: row = H-row, col via l16 (64B coalesced)
#pragma unroll
        for (int i = 0; i < 8; ++i) {
#pragma unroll
            for (int j = 0; j < 4; ++j) {
#pragma unroll
                for (int r = 0; r < 4; ++r) {
                    int row = bm + wr + i * 16 + fr + r;
                    int col = bn + wcc + j * 16 + l16;
                    size_t o = (size_t)row * 512 + col;
                    ((float*)Cv)[o] = acc[i][j][r] + Dv[col] * bf2f(Xb[tidx(row, col)]);
                }
            }
        }
    }
}

// Scan pass A: block = (chunk c, h-slab s); threads = 16 b x 16 h-pairs.
// Batch-8 loads (addresses independent of recurrence) to hide HBM latency.
// Writes raw chunk end-sums S_c to WS_CARRY (read-only thereafter).
__global__ __launch_bounds__(256) void scan_local(const float* __restrict__ nu_log,
        const float* __restrict__ theta_log, float* __restrict__ ws) {
    const int c = blockIdx.x;
    const int s = blockIdx.y;
    const int b = threadIdx.x >> 4;
    const int h0 = s * 32 + (threadIdx.x & 15) * 2;
    float lr[2], li[2];
#pragma unroll
    for (int q = 0; q < 2; ++q) {
        float nu = expf(nu_log[h0 + q]);
        float th = expf(theta_log[h0 + q]);
        float r  = expf(-nu);
        lr[q] = r * cosf(th); li[q] = r * sinf(th);
    }
    const ushort_t* Bu = (const ushort_t*)(ws + WS_BU);
    float hr[2] = {0.f, 0.f}, hi[2] = {0.f, 0.f};
    for (int l0 = 0; l0 < CHUNK; l0 += 8) {
        unsigned int vre[8], vim[8];
#pragma unroll
        for (int u = 0; u < 8; ++u) {
            int n = (c * CHUNK + l0 + u) * B_DIM + b;
            vre[u] = *(const unsigned int*)(&Bu[tidx(n, h0)]);
            vim[u] = *(const unsigned int*)(&Bu[tidx(n, h0 + 256)]);
        }
#pragma unroll
        for (int u = 0; u < 8; ++u) {
#pragma unroll
            for (int q = 0; q < 2; ++q) {
                float br = bf2f((ushort_t)(q ? (vre[u] >> 16) : (vre[u] & 0xffff)));
                float bi = bf2f((ushort_t)(q ? (vim[u] >> 16) : (vim[u] & 0xffff)));
                float nr = fmaf(lr[q], hr[q], fmaf(-li[q], hi[q], br));
                float ni = fmaf(lr[q], hi[q], fmaf(li[q], hr[q], bi));
                hr[q] = nr; hi[q] = ni;
            }
        }
    }
    size_t cb = (size_t)(c * B_DIM + b) * KC;
    *(float2*)(&ws[WS_CARRY + cb + h0])       = make_float2(hr[0], hr[1]);
    *(float2*)(&ws[WS_CARRY + cb + 256 + h0]) = make_float2(hi[0], hi[1]);
}

// Pass C (carry FUSED): block (c,s) computes its own carry-in
//   cr = h0; for j<c: cr = lam^64*cr + S_j   (S_j L2-resident, 256KB)
// then replays chunk c from cr, overwriting Bu in place (tiled bf16).
// Blocks with c==31 write h_final (= replay end state) planar to out tail.
__global__ __launch_bounds__(256) void scan_apply(const float* __restrict__ nu_log,
        const float* __restrict__ theta_log, float* __restrict__ ws,
        const float* __restrict__ h_re, const float* __restrict__ h_im,
        float* __restrict__ out, int out_size) {
    const int c = blockIdx.x;
    const int s = blockIdx.y;
    const int b = threadIdx.x >> 4;
    const int h0 = s * 32 + (threadIdx.x & 15) * 2;
    float lr[2], li[2], Lr[2], Li[2];
#pragma unroll
    for (int q = 0; q < 2; ++q) {
        float nu = expf(nu_log[h0 + q]);
        float th = expf(theta_log[h0 + q]);
        float r  = expf(-nu);
        lr[q] = r * cosf(th); li[q] = r * sinf(th);
        float rL  = expf(-64.f * nu);
        float thL = 64.f * th;
        Lr[q] = rL * cosf(thL); Li[q] = rL * sinf(thL);
    }
    // carry-in: start from initial state, fold chunk sums 0..c-1
    float hr[2], hi[2];
#pragma unroll
    for (int q = 0; q < 2; ++q) {
        hr[q] = h_re[b * H_DIM + h0 + q];
        hi[q] = h_im[b * H_DIM + h0 + q];
    }
    for (int j = 0; j < c; ++j) {
        size_t cb = (size_t)(j * B_DIM + b) * KC;
        float2 sre = *(const float2*)(&ws[WS_CARRY + cb + h0]);
        float2 sim = *(const float2*)(&ws[WS_CARRY + cb + 256 + h0]);
        float sr[2] = {sre.x, sre.y}, si[2] = {sim.x, sim.y};
#pragma unroll
        for (int q = 0; q < 2; ++q) {
            float nr = fmaf(Lr[q], hr[q], fmaf(-Li[q], hi[q], sr[q]));
            float ni = fmaf(Lr[q], hi[q], fmaf(Li[q], hr[q], si[q]));
            hr[q] = nr; hi[q] = ni;
        }
    }
    // replay chunk c
    ushort_t* Bu = (ushort_t*)(ws + WS_BU);
    for (int l0 = 0; l0 < CHUNK; l0 += 8) {
        unsigned int vre[8], vim[8];
        int ire[8], iim[8];
#pragma unroll
        for (int u = 0; u < 8; ++u) {
            int n = (c * CHUNK + l0 + u) * B_DIM + b;
            ire[u] = tidx(n, h0);
            iim[u] = tidx(n, h0 + 256);
            vre[u] = *(const unsigned int*)(&Bu[ire[u]]);
            vim[u] = *(const unsigned int*)(&Bu[iim[u]]);
        }
#pragma unroll
        for (int u = 0; u < 8; ++u) {
#pragma unroll
            for (int q = 0; q < 2; ++q) {
                float br = bf2f((ushort_t)(q ? (vre[u] >> 16) : (vre[u] & 0xffff)));
                float bi = bf2f((ushort_t)(q ? (vim[u] >> 16) : (vim[u] & 0xffff)));
                float nr = fmaf(lr[q], hr[q], fmaf(-li[q], hi[q], br));
                float ni = fmaf(lr[q], hi[q], fmaf(li[q], hr[q], bi));
                hr[q] = nr; hi[q] = ni;
            }
            *(unsigned int*)(&Bu[ire[u]]) =
                (unsigned int)f2bf(hr[0]) | ((unsigned int)f2bf(hr[1]) << 16);
            *(unsigned int*)(&Bu[iim[u]]) =
                (unsigned int)f2bf(hi[0]) | ((unsigned int)f2bf(hi[1]) << 16);
        }
    }
    // h_final: replay end state of the last chunk, planar re/im
    if (c == NCHUNK - 1) {
        const size_t base = (size_t)T_DIM * B_DIM * M_DIM;
#pragma unroll
        for (int q = 0; q < 2; ++q) {
            size_t idx = (size_t)b * H_DIM + h0 + q;
            size_t ore = base + idx;
            size_t oim = base + (size_t)B_DIM * H_DIM + idx;
            if (ore < (size_t)out_size) out[ore] = hr[q];
            if (oim < (size_t)out_size) out[oim] = hi[q];
        }
    }
}

extern "C" void kernel_launch(void* const* d_in, const int* in_sizes, int n_in,
                              void* d_out, int out_size, void* d_ws, size_t ws_size,
                              hipStream_t stream) {
    const float* inputs    = (const float*)d_in[0];
    const float* h_re      = (const float*)d_in[1];
    const float* h_im      = (const float*)d_in[2];
    const float* nu_log    = (const float*)d_in[3];
    const float* theta_log = (const float*)d_in[4];
    const float* gamma_log = (const float*)d_in[5];
    const float* B_re      = (const float*)d_in[6];
    const float* B_im      = (const float*)d_in[7];
    const float* C_re      = (const float*)d_in[8];
    const float* C_im      = (const float*)d_in[9];
    const float* Dv        = (const float*)d_in[10];
    float* out = (float*)d_out;
    float* ws  = (float*)d_ws;
    ushort_t* wb = (ushort_t*)(ws + WS_WB_BF);
    ushort_t* wc = (ushort_t*)(ws + WS_WC_BF);
    ushort_t* xb = (ushort_t*)(ws + WS_XB);
    ushort_t* bu = (ushort_t*)(ws + WS_BU);

    prep_all<<<9216, 256, 0, stream>>>(inputs, xb, B_re, B_im, gamma_log,
                                       C_re, C_im, wb, wc);

    // GEMM1: Bu = X . Wb^T (swapped MFMA; tiled Bu out)
    gemm_mfma<0><<<256, 512, 0, stream>>>(xb, wb, (void*)bu, nullptr, nullptr);

    scan_local<<<dim3(NCHUNK, 8), 256, 0, stream>>>(nu_log, theta_log, ws);
    scan_apply<<<dim3(NCHUNK, 8), 256, 0, stream>>>(nu_log, theta_log, ws,
                                                    h_re, h_im, out, out_size);

    // GEMM2: Y = H . Wc^T + D*x  (fp32 out + Xb epilogue)
    gemm_mfma<1><<<256, 512, 0, stream>>>(bu, wc, (void*)out, Dv, xb);
}

// Round 18
// 101.857 us; speedup vs baseline: 1.1820x; 1.0564x over previous
//
#include <hip/hip_runtime.h>
#include <hip/hip_bf16.h>
#include <math.h>

#define T_DIM 2048
#define B_DIM 16
#define M_DIM 512
#define H_DIM 256
#define KC 512
#define K_DIM 512
#define CHUNK 64
#define NCHUNK 32
#define NTILE 16            // K / 32 (pre-tiled granule count per 128-panel)

typedef unsigned short ushort_t;
typedef __attribute__((ext_vector_type(8))) short short8;
typedef __attribute__((ext_vector_type(8))) unsigned short ushort8;
typedef __attribute__((ext_vector_type(4))) float f32x4;

// ---- workspace layout (float offsets); total 17301504 floats = 69.2 MB ----
#define WS_CARRY 0            // 262144 floats (32*16*512)
#define WS_WB_BF 262144       // 262144 ushorts tiled
#define WS_WC_BF 393216       // 262144 ushorts tiled
#define WS_XB    524288       // 16777216 ushorts: X bf16 TILED
#define WS_BU    8912896      // 16777216 ushorts: Bu TILED, then H in place

// tiled index (ushorts): element (n,k) -> ((n/128)*16 + k/32)*4096 +
//   ((k/8)%4)*1024 + (n%128)*8 + k%8   — linear LDS staging order.
__device__ inline int tidx(int n, int k) {
    return (((n >> 7) * 16 + (k >> 5)) << 12) + (((k >> 3) & 3) << 10)
         + ((n & 127) << 3) + (k & 7);
}

__device__ inline ushort_t f2bf(float f) {
    __hip_bfloat16 h = __float2bfloat16(f);
    return *reinterpret_cast<ushort_t*>(&h);
}
__device__ inline float bf2f(ushort_t u) {
    union { unsigned int i; float f; } v;
    v.i = ((unsigned int)u) << 16;
    return v.f;
}

// Merged prep: blocks [0,8192) convert X fp32 -> bf16 TILED; blocks
// [8192,9216) build the bf16 pre-tiled weights.
__global__ __launch_bounds__(256) void prep_all(
        const float* __restrict__ X, ushort_t* __restrict__ Xb,
        const float* __restrict__ B_re, const float* __restrict__ B_im,
        const float* __restrict__ gamma_log,
        const float* __restrict__ C_re, const float* __restrict__ C_im,
        ushort_t* __restrict__ wb, ushort_t* __restrict__ wc) {
    int bid = blockIdx.x;
    if (bid < 8192) {
        int f = bid * 256 + threadIdx.x;          // 0..2097151
        int n = f >> 6, ko = f & 63;
        const float* p = X + (size_t)n * 512 + ko * 8;
        float4 a = *(const float4*)p;
        float4 b = *(const float4*)(p + 4);
        ushort8 u;
        u[0] = f2bf(a.x); u[1] = f2bf(a.y); u[2] = f2bf(a.z); u[3] = f2bf(a.w);
        u[4] = f2bf(b.x); u[5] = f2bf(b.y); u[6] = f2bf(b.z); u[7] = f2bf(b.w);
        *(ushort8*)(&Xb[(((n >> 7) * 16 + (ko >> 2)) << 12) + ((ko & 3) << 10)
                        + ((n & 127) << 3)]) = u;
    } else {
        int idx = (bid - 8192) * 256 + threadIdx.x;  // 0..262143
        int e    = idx & 7;
        int slot = (idx >> 3) & 511;
        int row  = slot & 127;
        int ks   = slot >> 7;
        int t    = (idx >> 12) & 15;
        int blk  = idx >> 16;
        int j = blk * 128 + row;
        int k = t * 32 + ks * 8 + e;
        float v;
        if (j < 256) v = expf(gamma_log[j])       * B_re[j * 512 + k];
        else         v = expf(gamma_log[j - 256]) * B_im[(j - 256) * 512 + k];
        wb[idx] = f2bf(v);
        float w;
        if (k < 256) w =  C_re[j * 256 + k];
        else         w = -C_im[j * 256 + (k - 256)];
        wc[idx] = f2bf(w);
    }
}

// NT GEMM via MFMA bf16, 256x256 tile, BK=64, 8 waves (512 thr).
// Proven 2-phase structure (2 LDS dbufs, unroll-2 static indices, plain
// __syncthreads) — per K-step compute window is 64 MFMA/wave (~620cy/SIMD)
// matching staging latency, 8 drains total. Both operands staged via
// global_load_lds with the chunk-contiguous map (per-instruction lane
// stride exactly 16B, m104). A 256x64 tile = 4 contiguous 8KB sub-tiles;
// each staged by 512 threads x 16B (1 gload_lds per thread per sub-tile).
// Grid 1-D 256: id = g*16 + j*8 + x -> rb = g*8+x (0..127), nb = j (0..1);
// the 2 col-panels of a row-panel are spaced 8 ids -> same XCD.
// MODE 0 (GEMM1): swapped operands mfma(W,X), acc[i:4][j:8], packed uint2
//   stores into TILED Bu. MODE 1 (GEMM2): acc[i:8][j:4], fp32 natural out
//   + D[col]*Xb epilogue.
template <int MODE>
__global__ __launch_bounds__(512) void gemm_mfma(
    const ushort_t* __restrict__ A, const ushort_t* __restrict__ W,
    void* __restrict__ Cv, const float* __restrict__ Dv,
    const ushort_t* __restrict__ Xb) {
    __shared__ ushort_t Asl[2][4][4096];   // [buf][q*2+kk][slot] : 64KB
    __shared__ ushort_t Bsl[2][4][4096];   // 64KB
    const int tid = threadIdx.x;           // 0..511
    const int id = blockIdx.x;
    const int rb = ((id >> 4) << 3) + (id & 7);   // row-panel-pair 0..127
    const int nb = (id >> 3) & 1;                 // col-panel-pair 0..1
    const int bm = rb << 8, bn = nb << 8;
    const int lane = tid & 63, wid = tid >> 6;    // 8 waves
    const int wr  = (wid >> 2) << 7;       // 0 / 128
    const int wcc = (wid & 3) << 6;        // 0,64,128,192
    const int l16 = lane & 15, ksl = lane >> 4;

    f32x4 acc[MODE == 0 ? 4 : 8][MODE == 0 ? 8 : 4] = {};

    auto stage = [&](int t, int buf) {
#pragma unroll
        for (int q = 0; q < 2; ++q) {
#pragma unroll
            for (int kk = 0; kk < 2; ++kk) {
                size_t ab = ((size_t)((2 * rb + q) * NTILE + (2 * t + kk))) * 4096;
                __builtin_amdgcn_global_load_lds(
                    (const __attribute__((address_space(1))) void*)(A + ab + tid * 8),
                    (__attribute__((address_space(3))) void*)(&Asl[buf][q * 2 + kk][tid * 8]),
                    16, 0, 0);
                size_t bb = ((size_t)((2 * nb + q) * NTILE + (2 * t + kk))) * 4096;
                __builtin_amdgcn_global_load_lds(
                    (const __attribute__((address_space(1))) void*)(W + bb + tid * 8),
                    (__attribute__((address_space(3))) void*)(&Bsl[buf][q * 2 + kk][tid * 8]),
                    16, 0, 0);
            }
        }
    };

    stage(0, 0);
    __syncthreads();

    int cur = 0;
#pragma unroll 2
    for (int t = 0; t < 8; ++t) {
        const int nxt = cur ^ 1;
        if (t + 1 < 8) stage(t + 1, nxt);
#pragma unroll
        for (int kk = 0; kk < 2; ++kk) {
            short8 afr[8], bfr[4];
#pragma unroll
            for (int m = 0; m < 8; ++m) {
                int row = wr + m * 16 + l16;       // 0..255
                afr[m] = *(const short8*)(&Asl[cur][(row >> 7) * 2 + kk]
                                              [ksl * 1024 + (row & 127) * 8]);
            }
#pragma unroll
            for (int n = 0; n < 4; ++n) {
                int col = wcc + n * 16 + l16;      // 0..255
                bfr[n] = *(const short8*)(&Bsl[cur][(col >> 7) * 2 + kk]
                                              [ksl * 1024 + (col & 127) * 8]);
            }
            if constexpr (MODE == 0) {
#pragma unroll
                for (int i = 0; i < 4; ++i)       // i: W-frag (k axis)
#pragma unroll
                    for (int j = 0; j < 8; ++j)   // j: X-frag (n axis)
                        acc[i][j] = __builtin_amdgcn_mfma_f32_16x16x32_bf16(
                            bfr[i], afr[j], acc[i][j], 0, 0, 0);
            } else {
#pragma unroll
                for (int i = 0; i < 8; ++i)       // i: A-frag (H rows)
#pragma unroll
                    for (int j = 0; j < 4; ++j)   // j: W-frag (out cols)
                        acc[i][j] = __builtin_amdgcn_mfma_f32_16x16x32_bf16(
                            afr[i], bfr[j], acc[i][j], 0, 0, 0);
            }
        }
        __syncthreads();
        cur = nxt;
    }

    const int fr = (lane >> 4) << 2;
    if constexpr (MODE == 0) {
        // D row axis = W-col k (4 consecutive), D col axis (l16) = X-row n.
        ushort_t* Bu = (ushort_t*)Cv;
#pragma unroll
        for (int i = 0; i < 4; ++i) {
            int k0 = bn + wcc + i * 16 + fr;      // 4-aligned k quad
#pragma unroll
            for (int j = 0; j < 8; ++j) {
                int n = bm + wr + j * 16 + l16;
                uint2 p;
                p.x = (unsigned int)f2bf(acc[i][j][0])
                    | ((unsigned int)f2bf(acc[i][j][1]) << 16);
                p.y = (unsigned int)f2bf(acc[i][j][2])
                    | ((unsigned int)f2bf(acc[i][j][3]) << 16);
                size_t off = ((size_t)((n >> 7) * 16 + (k0 >> 5)) << 12)
                           + (((k0 >> 3) & 3) << 10) + ((n & 127) << 3) + (k0 & 7);
                *(uint2*)(&Bu[off]) = p;
            }
        }
    } else {
        // natural fp32 out: row = H-row, col via l16 (64B coalesced)
#pragma unroll
        for (int i = 0; i < 8; ++i) {
#pragma unroll
            for (int j = 0; j < 4; ++j) {
#pragma unroll
                for (int r = 0; r < 4; ++r) {
                    int row = bm + wr + i * 16 + fr + r;
                    int col = bn + wcc + j * 16 + l16;
                    size_t o = (size_t)row * 512 + col;
                    ((float*)Cv)[o] = acc[i][j][r] + Dv[col] * bf2f(Xb[tidx(row, col)]);
                }
            }
        }
    }
}

// Scan pass A: block = (chunk c, h-slab s); threads = 16 b x 16 h-pairs.
// Batch-8 loads (addresses independent of recurrence) to hide HBM latency.
__global__ __launch_bounds__(256) void scan_local(const float* __restrict__ nu_log,
        const float* __restrict__ theta_log, float* __restrict__ ws) {
    const int c = blockIdx.x;
    const int s = blockIdx.y;
    const int b = threadIdx.x >> 4;
    const int h0 = s * 32 + (threadIdx.x & 15) * 2;
    float lr[2], li[2];
#pragma unroll
    for (int q = 0; q < 2; ++q) {
        float nu = expf(nu_log[h0 + q]);
        float th = expf(theta_log[h0 + q]);
        float r  = expf(-nu);
        lr[q] = r * cosf(th); li[q] = r * sinf(th);
    }
    const ushort_t* Bu = (const ushort_t*)(ws + WS_BU);
    float hr[2] = {0.f, 0.f}, hi[2] = {0.f, 0.f};
    for (int l0 = 0; l0 < CHUNK; l0 += 8) {
        unsigned int vre[8], vim[8];
#pragma unroll
        for (int u = 0; u < 8; ++u) {
            int n = (c * CHUNK + l0 + u) * B_DIM + b;
            vre[u] = *(const unsigned int*)(&Bu[tidx(n, h0)]);
            vim[u] = *(const unsigned int*)(&Bu[tidx(n, h0 + 256)]);
        }
#pragma unroll
        for (int u = 0; u < 8; ++u) {
#pragma unroll
            for (int q = 0; q < 2; ++q) {
                float br = bf2f((ushort_t)(q ? (vre[u] >> 16) : (vre[u] & 0xffff)));
                float bi = bf2f((ushort_t)(q ? (vim[u] >> 16) : (vim[u] & 0xffff)));
                float nr = fmaf(lr[q], hr[q], fmaf(-li[q], hi[q], br));
                float ni = fmaf(lr[q], hi[q], fmaf(li[q], hr[q], bi));
                hr[q] = nr; hi[q] = ni;
            }
        }
    }
    size_t cb = (size_t)(c * B_DIM + b) * KC;
    *(float2*)(&ws[WS_CARRY + cb + h0])       = make_float2(hr[0], hr[1]);
    *(float2*)(&ws[WS_CARRY + cb + 256 + h0]) = make_float2(hi[0], hi[1]);
}

// Pass B: sequential over 32 chunk aggregates; h_final planar re/im to out tail.
__global__ __launch_bounds__(256) void scan_carry(const float* __restrict__ nu_log,
        const float* __restrict__ theta_log, float* __restrict__ ws,
        const float* __restrict__ h_re, const float* __restrict__ h_im,
        float* __restrict__ out, int out_size) {
    const int b = blockIdx.x;
    const int h = threadIdx.x;
    const float nu = expf(nu_log[h]);
    const float th = expf(theta_log[h]);
    const float rL  = expf(-64.f * nu);
    const float thL = 64.f * th;
    const float Lr = rL * cosf(thL), Li = rL * sinf(thL);
    float cr = h_re[b * H_DIM + h], ci = h_im[b * H_DIM + h];
    for (int c = 0; c < NCHUNK; ++c) {
        size_t cidx = ((size_t)(c * B_DIM + b)) * KC + h;
        float sr = ws[WS_CARRY + cidx], si = ws[WS_CARRY + cidx + 256];
        ws[WS_CARRY + cidx]       = cr;
        ws[WS_CARRY + cidx + 256] = ci;
        float nr = fmaf(Lr, cr, fmaf(-Li, ci, sr));
        float ni = fmaf(Lr, ci, fmaf(Li, cr, si));
        cr = nr; ci = ni;
    }
    const size_t base = (size_t)T_DIM * B_DIM * M_DIM;
    const size_t idx  = (size_t)b * H_DIM + h;
    size_t ore = base + idx;
    size_t oim = base + (size_t)B_DIM * H_DIM + idx;
    if (ore < (size_t)out_size) out[ore] = cr;
    if (oim < (size_t)out_size) out[oim] = ci;
}

// Pass C: replay chunk from carry-in; overwrite Bu IN PLACE (tiled) with h_t.
__global__ __launch_bounds__(256) void scan_apply(const float* __restrict__ nu_log,
        const float* __restrict__ theta_log, float* __restrict__ ws) {
    const int c = blockIdx.x;
    const int s = blockIdx.y;
    const int b = threadIdx.x >> 4;
    const int h0 = s * 32 + (threadIdx.x & 15) * 2;
    float lr[2], li[2];
#pragma unroll
    for (int q = 0; q < 2; ++q) {
        float nu = expf(nu_log[h0 + q]);
        float th = expf(theta_log[h0 + q]);
        float r  = expf(-nu);
        lr[q] = r * cosf(th); li[q] = r * sinf(th);
    }
    ushort_t* Bu = (ushort_t*)(ws + WS_BU);
    size_t cb = (size_t)(c * B_DIM + b) * KC;
    float2 f2r = *(const float2*)(&ws[WS_CARRY + cb + h0]);
    float2 f2i = *(const float2*)(&ws[WS_CARRY + cb + 256 + h0]);
    float hr[2] = {f2r.x, f2r.y}, hi[2] = {f2i.x, f2i.y};
    for (int l0 = 0; l0 < CHUNK; l0 += 8) {
        unsigned int vre[8], vim[8];
        int ire[8], iim[8];
#pragma unroll
        for (int u = 0; u < 8; ++u) {
            int n = (c * CHUNK + l0 + u) * B_DIM + b;
            ire[u] = tidx(n, h0);
            iim[u] = tidx(n, h0 + 256);
            vre[u] = *(const unsigned int*)(&Bu[ire[u]]);
            vim[u] = *(const unsigned int*)(&Bu[iim[u]]);
        }
#pragma unroll
        for (int u = 0; u < 8; ++u) {
#pragma unroll
            for (int q = 0; q < 2; ++q) {
                float br = bf2f((ushort_t)(q ? (vre[u] >> 16) : (vre[u] & 0xffff)));
                float bi = bf2f((ushort_t)(q ? (vim[u] >> 16) : (vim[u] & 0xffff)));
                float nr = fmaf(lr[q], hr[q], fmaf(-li[q], hi[q], br));
                float ni = fmaf(lr[q], hi[q], fmaf(li[q], hr[q], bi));
                hr[q] = nr; hi[q] = ni;
            }
            *(unsigned int*)(&Bu[ire[u]]) =
                (unsigned int)f2bf(hr[0]) | ((unsigned int)f2bf(hr[1]) << 16);
            *(unsigned int*)(&Bu[iim[u]]) =
                (unsigned int)f2bf(hi[0]) | ((unsigned int)f2bf(hi[1]) << 16);
        }
    }
}

extern "C" void kernel_launch(void* const* d_in, const int* in_sizes, int n_in,
                              void* d_out, int out_size, void* d_ws, size_t ws_size,
                              hipStream_t stream) {
    const float* inputs    = (const float*)d_in[0];
    const float* h_re      = (const float*)d_in[1];
    const float* h_im      = (const float*)d_in[2];
    const float* nu_log    = (const float*)d_in[3];
    const float* theta_log = (const float*)d_in[4];
    const float* gamma_log = (const float*)d_in[5];
    const float* B_re      = (const float*)d_in[6];
    const float* B_im      = (const float*)d_in[7];
    const float* C_re      = (const float*)d_in[8];
    const float* C_im      = (const float*)d_in[9];
    const float* Dv        = (const float*)d_in[10];
    float* out = (float*)d_out;
    float* ws  = (float*)d_ws;
    ushort_t* wb = (ushort_t*)(ws + WS_WB_BF);
    ushort_t* wc = (ushort_t*)(ws + WS_WC_BF);
    ushort_t* xb = (ushort_t*)(ws + WS_XB);
    ushort_t* bu = (ushort_t*)(ws + WS_BU);

    prep_all<<<9216, 256, 0, stream>>>(inputs, xb, B_re, B_im, gamma_log,
                                       C_re, C_im, wb, wc);

    // GEMM1: Bu = X . Wb^T (swapped-operand MFMA, packed tiled stores)
    gemm_mfma<0><<<256, 512, 0, stream>>>(xb, wb, (void*)bu, nullptr, nullptr);

    scan_local<<<dim3(NCHUNK, 8), 256, 0, stream>>>(nu_log, theta_log, ws);
    scan_carry<<<B_DIM, 256, 0, stream>>>(nu_log, theta_log, ws, h_re, h_im,
                                          out, out_size);
    scan_apply<<<dim3(NCHUNK, 8), 256, 0, stream>>>(nu_log, theta_log, ws);

    // GEMM2: Y = H . Wc^T + D*x  (fp32 natural out)
    gemm_mfma<1><<<256, 512, 0, stream>>>(bu, wc, (void*)out, Dv, xb);
}